// Round 1
// baseline (674.588 us; speedup 1.0000x reference)
//
#include <hip/hip_runtime.h>
#include <hip/hip_bf16.h>

#define H 128

// ---------------- graph preprocessing ----------------

__global__ void initK(int* deg_out, int* deg_in, int* fill, int n) {
    int i = blockIdx.x * 256 + threadIdx.x;
    if (i < n) { deg_out[i] = 1; deg_in[i] = 1; fill[i] = 0; }
}

__global__ void degK(const int* __restrict__ src, const int* __restrict__ dst,
                     int* deg_out, int* deg_in, int E) {
    int e = blockIdx.x * 256 + threadIdx.x;
    if (e < E) {
        atomicAdd(&deg_out[src[e]], 1);
        atomicAdd(&deg_in[dst[e]], 1);
    }
}

__global__ void normK(const int* __restrict__ deg_out, const int* __restrict__ deg_in,
                      float* norm_s, float* norm_d, int n) {
    int i = blockIdx.x * 256 + threadIdx.x;
    if (i < n) {
        norm_s[i] = rsqrtf((float)deg_out[i]);
        norm_d[i] = rsqrtf((float)deg_in[i]);
    }
}

// exclusive scan of (deg_in[i]-1) -> rowptr.  Phase 1: 1024 elems/block.
__global__ __launch_bounds__(256) void scan1(const int* __restrict__ deg_in,
                                             int* __restrict__ rowptr,
                                             int* __restrict__ bsum, int n) {
    __shared__ int sh[256];
    int t = threadIdx.x;
    int base = blockIdx.x * 1024 + t * 4;
    int v[4];
#pragma unroll
    for (int i = 0; i < 4; i++) {
        int idx = base + i;
        v[i] = (idx < n) ? (deg_in[idx] - 1) : 0;
    }
    int s = v[0] + v[1] + v[2] + v[3];
    sh[t] = s;
    __syncthreads();
    for (int off = 1; off < 256; off <<= 1) {
        int x = (t >= off) ? sh[t - off] : 0;
        __syncthreads();
        sh[t] += x;
        __syncthreads();
    }
    int run = sh[t] - s;  // exclusive prefix of this thread's chunk
#pragma unroll
    for (int i = 0; i < 4; i++) {
        int idx = base + i;
        if (idx < n) rowptr[idx] = run;
        run += v[i];
    }
    if (t == 255) bsum[blockIdx.x] = sh[255];
}

// Phase 2: scan block sums (<=64 blocks) in one wave
__global__ void scan2(int* bsum, int nb) {
    int lane = threadIdx.x;
    int v = (lane < nb) ? bsum[lane] : 0;
    int orig = v;
    for (int off = 1; off < 64; off <<= 1) {
        int x = __shfl_up(v, off, 64);
        if (lane >= off) v += x;
    }
    if (lane < nb) bsum[lane] = v - orig;  // exclusive
}

// Phase 3: add block offsets, write rowptr[n]=E
__global__ void scan3(int* rowptr, const int* __restrict__ bsum, int n, int E) {
    int i = blockIdx.x * 256 + threadIdx.x;
    if (i < n) rowptr[i] += bsum[i >> 10];
    if (i == 0) rowptr[n] = E;
}

__global__ void fillK(const int* __restrict__ src, const int* __restrict__ dst,
                      const int* __restrict__ rowptr, int* fill, int* esrc, int E) {
    int e = blockIdx.x * 256 + threadIdx.x;
    if (e < E) {
        int d = dst[e];
        int p = rowptr[d] + atomicAdd(&fill[d], 1);
        esrc[p] = src[e];
    }
}

// ---------------- compute ----------------

// Y[i,c] = norm_s[i] * sum_k X[i,k] * W[k,c]     (H=128 cols)
// block: 256 threads = 128 cols x 2 row-halves; 32 rows/block, 16 acc/thread
__global__ __launch_bounds__(256) void gemm_norm(const float* __restrict__ X,
                                                 const float* __restrict__ W,
                                                 const float* __restrict__ norm_s,
                                                 float* __restrict__ Y, int N, int D) {
    __shared__ float xs[32][20];  // +4 pad keeps float4 alignment (20*4=80B, 16B-aligned)
    int t = threadIdx.x;
    int c = t & 127;
    int rh = t >> 7;  // 0/1
    int rowbase = blockIdx.x * 32;
    float acc[16];
#pragma unroll
    for (int r = 0; r < 16; r++) acc[r] = 0.f;

    for (int k0 = 0; k0 < D; k0 += 16) {
        __syncthreads();
        if (t < 128) {  // 128 float4 = 32 rows x 16 k
            int r = t >> 2;
            int q = t & 3;
            int row = rowbase + r;
            float4 v = make_float4(0.f, 0.f, 0.f, 0.f);
            if (row < N) v = *(const float4*)(X + (size_t)row * D + k0 + q * 4);
            *(float4*)&xs[r][q * 4] = v;
        }
        __syncthreads();
        float wv[16];
#pragma unroll
        for (int kk = 0; kk < 16; kk++) wv[kk] = W[(size_t)(k0 + kk) * H + c];
#pragma unroll
        for (int kk = 0; kk < 16; kk += 4) {
#pragma unroll
            for (int r = 0; r < 16; r++) {
                float4 xv = *(const float4*)&xs[rh * 16 + r][kk];  // wave-broadcast
                acc[r] = fmaf(xv.x, wv[kk], acc[r]);
                acc[r] = fmaf(xv.y, wv[kk + 1], acc[r]);
                acc[r] = fmaf(xv.z, wv[kk + 2], acc[r]);
                acc[r] = fmaf(xv.w, wv[kk + 3], acc[r]);
            }
        }
    }
#pragma unroll
    for (int r = 0; r < 16; r++) {
        int row = rowbase + rh * 16 + r;
        if (row < N) Y[(size_t)row * H + c] = acc[r] * norm_s[row];
    }
}

// Out[i] = act( norm_d[i] * (Y[i] + sum_{e:dst=i} Y[src_e]) + b )
// one wave per node, float2 per lane
__global__ __launch_bounds__(256) void aggK(const float* __restrict__ Y,
                                            const int* __restrict__ rowptr,
                                            const int* __restrict__ esrc,
                                            const float* __restrict__ norm_d,
                                            const float* __restrict__ bias,
                                            float* __restrict__ Out, int N, int relu) {
    int wave = threadIdx.x >> 6;
    int lane = threadIdx.x & 63;
    int node = blockIdx.x * 4 + wave;
    if (node >= N) return;
    int beg = rowptr[node], end = rowptr[node + 1];
    const float2* y2 = (const float2*)Y;
    float2 acc = y2[(size_t)node * 64 + lane];  // self-loop
    int j = beg;
    for (; j + 1 < end; j += 2) {  // 2-way unroll for MLP latency overlap
        int s0 = esrc[j], s1 = esrc[j + 1];
        float2 v0 = y2[(size_t)s0 * 64 + lane];
        float2 v1 = y2[(size_t)s1 * 64 + lane];
        acc.x += v0.x + v1.x;
        acc.y += v0.y + v1.y;
    }
    if (j < end) {
        int s0 = esrc[j];
        float2 v0 = y2[(size_t)s0 * 64 + lane];
        acc.x += v0.x;
        acc.y += v0.y;
    }
    float nd = norm_d[node];
    float2 b = ((const float2*)bias)[lane];
    float ox = fmaf(acc.x, nd, b.x);
    float oy = fmaf(acc.y, nd, b.y);
    if (relu) { ox = ox > 0.f ? ox : 0.f; oy = oy > 0.f ? oy : 0.f; }
    ((float2*)Out)[(size_t)node * 64 + lane] = make_float2(ox, oy);
}

// ---------------- host ----------------

static inline int ceil_div(int a, int b) { return (a + b - 1) / b; }

struct TypeBufs {
    int *deg_out, *deg_in, *fill, *rowptr, *bsum, *esrc;
    float *norm_s, *norm_d, *y, *h;
};

extern "C" void kernel_launch(void* const* d_in, const int* in_sizes, int n_in,
                              void* d_out, int out_size, void* d_ws, size_t ws_size,
                              hipStream_t stream) {
    (void)n_in; (void)out_size; (void)ws_size;
    const float* feat_a = (const float*)d_in[0];
    const float* feat_b = (const float*)d_in[1];
    const int* src_a = (const int*)d_in[2];
    const int* dst_a = (const int*)d_in[3];
    const int* src_b = (const int*)d_in[4];
    const int* dst_b = (const int*)d_in[5];
    const float* Wa0 = (const float*)d_in[6];
    const float* ba0 = (const float*)d_in[7];
    const float* Wa1 = (const float*)d_in[8];
    const float* ba1 = (const float*)d_in[9];
    const float* Wb0 = (const float*)d_in[10];
    const float* bb0 = (const float*)d_in[11];
    const float* Wb1 = (const float*)d_in[12];
    const float* bb1 = (const float*)d_in[13];

    const int DA = in_sizes[6] / H;           // 256
    const int DB = in_sizes[10] / H;          // 128
    const int NA = in_sizes[0] / DA;          // 50000
    const int NB = in_sizes[1] / DB;          // 30000
    const int EA = in_sizes[2];               // 600000
    const int EB = in_sizes[4];               // 300000

    char* w = (char*)d_ws;
    auto carve = [&](size_t bytes) {
        void* p = (void*)w;
        w += (bytes + 255) & ~(size_t)255;
        return p;
    };
    auto carve_type = [&](int N, int E) {
        TypeBufs tb;
        tb.deg_out = (int*)carve((size_t)N * 4);
        tb.deg_in  = (int*)carve((size_t)N * 4);
        tb.fill    = (int*)carve((size_t)N * 4);
        tb.rowptr  = (int*)carve(((size_t)N + 1) * 4);
        tb.bsum    = (int*)carve(64 * 4);
        tb.esrc    = (int*)carve((size_t)E * 4);
        tb.norm_s  = (float*)carve((size_t)N * 4);
        tb.norm_d  = (float*)carve((size_t)N * 4);
        tb.y       = (float*)carve((size_t)N * H * 4);
        tb.h       = (float*)carve((size_t)N * H * 4);
        return tb;
    };
    TypeBufs A = carve_type(NA, EA);
    TypeBufs B = carve_type(NB, EB);

    float* out_a = (float*)d_out;
    float* out_b = out_a + (size_t)NA * H;

    auto run_type = [&](const TypeBufs& tb, const float* feat, const int* src, const int* dst,
                        const float* W0, const float* b0, const float* W1, const float* b1,
                        int N, int E, int D, float* out) {
        // graph prep
        initK<<<ceil_div(N, 256), 256, 0, stream>>>(tb.deg_out, tb.deg_in, tb.fill, N);
        degK<<<ceil_div(E, 256), 256, 0, stream>>>(src, dst, tb.deg_out, tb.deg_in, E);
        normK<<<ceil_div(N, 256), 256, 0, stream>>>(tb.deg_out, tb.deg_in, tb.norm_s, tb.norm_d, N);
        int nb = ceil_div(N, 1024);
        scan1<<<nb, 256, 0, stream>>>(tb.deg_in, tb.rowptr, tb.bsum, N);
        scan2<<<1, 64, 0, stream>>>(tb.bsum, nb);
        scan3<<<ceil_div(N, 256), 256, 0, stream>>>(tb.rowptr, tb.bsum, N, E);
        fillK<<<ceil_div(E, 256), 256, 0, stream>>>(src, dst, tb.rowptr, tb.fill, tb.esrc, E);
        // layer 0
        gemm_norm<<<ceil_div(N, 32), 256, 0, stream>>>(feat, W0, tb.norm_s, tb.y, N, D);
        aggK<<<ceil_div(N, 4), 256, 0, stream>>>(tb.y, tb.rowptr, tb.esrc, tb.norm_d, b0, tb.h, N, 1);
        // layer 1
        gemm_norm<<<ceil_div(N, 32), 256, 0, stream>>>(tb.h, W1, tb.norm_s, tb.y, N, H);
        aggK<<<ceil_div(N, 4), 256, 0, stream>>>(tb.y, tb.rowptr, tb.esrc, tb.norm_d, b1, out, N, 0);
    };

    run_type(A, feat_a, src_a, dst_a, Wa0, ba0, Wa1, ba1, NA, EA, DA, out_a);
    run_type(B, feat_b, src_b, dst_b, Wb0, bb0, Wb1, bb1, NB, EB, DB, out_b);
}

// Round 2
// 508.343 us; speedup vs baseline: 1.3270x; 1.3270x over previous
//
#include <hip/hip_runtime.h>
#include <hip/hip_bf16.h>

#define H 128
#define BK 64
#define LDSTR 72  // LDS row stride (bf16 elems): 144B -> 2-way bank alias (free)

typedef __bf16 bf16;
typedef __attribute__((ext_vector_type(8))) __bf16 bf16x8;
typedef __attribute__((ext_vector_type(4))) __bf16 bf16x4;
typedef __attribute__((ext_vector_type(4))) float floatx4;

// ---------------- graph preprocessing ----------------

__global__ void initK(int* deg_out, int* deg_in, int* fill, int n) {
    int i = blockIdx.x * 256 + threadIdx.x;
    if (i < n) { deg_out[i] = 1; deg_in[i] = 1; fill[i] = 0; }
}

__global__ void degK(const int* __restrict__ src, const int* __restrict__ dst,
                     int* deg_out, int* deg_in, int E) {
    int e = blockIdx.x * 256 + threadIdx.x;
    if (e < E) {
        atomicAdd(&deg_out[src[e]], 1);
        atomicAdd(&deg_in[dst[e]], 1);
    }
}

__global__ void normK(const int* __restrict__ deg_out, const int* __restrict__ deg_in,
                      float* norm_s, float* norm_d, int n) {
    int i = blockIdx.x * 256 + threadIdx.x;
    if (i < n) {
        norm_s[i] = rsqrtf((float)deg_out[i]);
        norm_d[i] = rsqrtf((float)deg_in[i]);
    }
}

__global__ __launch_bounds__(256) void scan1(const int* __restrict__ deg_in,
                                             int* __restrict__ rowptr,
                                             int* __restrict__ bsum, int n) {
    __shared__ int sh[256];
    int t = threadIdx.x;
    int base = blockIdx.x * 1024 + t * 4;
    int v[4];
#pragma unroll
    for (int i = 0; i < 4; i++) {
        int idx = base + i;
        v[i] = (idx < n) ? (deg_in[idx] - 1) : 0;
    }
    int s = v[0] + v[1] + v[2] + v[3];
    sh[t] = s;
    __syncthreads();
    for (int off = 1; off < 256; off <<= 1) {
        int x = (t >= off) ? sh[t - off] : 0;
        __syncthreads();
        sh[t] += x;
        __syncthreads();
    }
    int run = sh[t] - s;
#pragma unroll
    for (int i = 0; i < 4; i++) {
        int idx = base + i;
        if (idx < n) rowptr[idx] = run;
        run += v[i];
    }
    if (t == 255) bsum[blockIdx.x] = sh[255];
}

__global__ void scan2(int* bsum, int nb) {
    int lane = threadIdx.x;
    int v = (lane < nb) ? bsum[lane] : 0;
    int orig = v;
    for (int off = 1; off < 64; off <<= 1) {
        int x = __shfl_up(v, off, 64);
        if (lane >= off) v += x;
    }
    if (lane < nb) bsum[lane] = v - orig;
}

__global__ void scan3(int* rowptr, const int* __restrict__ bsum, int n, int E) {
    int i = blockIdx.x * 256 + threadIdx.x;
    if (i < n) rowptr[i] += bsum[i >> 10];
    if (i == 0) rowptr[n] = E;
}

__global__ void fillK(const int* __restrict__ src, const int* __restrict__ dst,
                      const int* __restrict__ rowptr, int* fill, int* esrc, int E) {
    int e = blockIdx.x * 256 + threadIdx.x;
    if (e < E) {
        int d = dst[e];
        int p = rowptr[d] + atomicAdd(&fill[d], 1);
        esrc[p] = src[e];
    }
}

// ---------------- weight prep: transpose + split-bf16 ----------------
// Wt_hi[c][k] = bf16(W[k][c]);  Wt_lo[c][k] = bf16(W[k][c] - hi)
__global__ void wconv(const float* __restrict__ W, bf16* __restrict__ Wth,
                      bf16* __restrict__ Wtl, int D) {
    int k = blockIdx.x;
    int c = threadIdx.x;
    float v = W[(size_t)k * H + c];
    bf16 h = (bf16)v;
    Wth[(size_t)c * D + k] = h;
    Wtl[(size_t)c * D + k] = (bf16)(v - (float)h);
}

// ---------------- MFMA GEMM: Y = (X * norm_s) @ W ----------------
// block: 256 thr = 4 waves; tile 64 rows x 128 cols; wave = 16 rows x 128 cols
// split-bf16: acc += Xh@Wh + Xl@Wh + Xh@Wl  (fp32-grade precision)
__global__ __launch_bounds__(256) void gemm_mfma(const float* __restrict__ X,
                                                 const bf16* __restrict__ Wth,
                                                 const bf16* __restrict__ Wtl,
                                                 const float* __restrict__ norm_s,
                                                 float* __restrict__ Y, int N, int D) {
    __shared__ bf16 Xh[64 * LDSTR], Xl[64 * LDSTR];
    __shared__ bf16 Wh[128 * LDSTR], Wl[128 * LDSTR];
    int t = threadIdx.x;
    int wv = t >> 6, lane = t & 63;
    int m = lane & 15, q = lane >> 4;
    int rowbase = blockIdx.x * 64;

    floatx4 acc[8];
#pragma unroll
    for (int c = 0; c < 8; c++) acc[c] = (floatx4)(0.f);

    for (int k0 = 0; k0 < D; k0 += BK) {
        __syncthreads();
        // stage X chunk: 64 rows x 64 k, fold norm_s, split hi/lo
        {
            int kq = (t & 15) * 4;
#pragma unroll
            for (int i = 0; i < 4; i++) {
                int r = (t >> 4) + i * 16;
                int grow = rowbase + r;
                float4 v = make_float4(0.f, 0.f, 0.f, 0.f);
                float ns = 0.f;
                if (grow < N) {
                    v = *(const float4*)(X + (size_t)grow * D + k0 + kq);
                    ns = norm_s[grow];
                }
                float xs4[4] = {v.x * ns, v.y * ns, v.z * ns, v.w * ns};
                bf16x4 hv, lv;
#pragma unroll
                for (int j = 0; j < 4; j++) {
                    bf16 h = (bf16)xs4[j];
                    hv[j] = h;
                    lv[j] = (bf16)(xs4[j] - (float)h);
                }
                *(bf16x4*)&Xh[r * LDSTR + kq] = hv;
                *(bf16x4*)&Xl[r * LDSTR + kq] = lv;
            }
        }
        // stage W chunk: 128 c x 64 k (already transposed/split in ws)
        {
            int ks = (t & 7) * 8;
            int rb = t >> 3;  // 0..31
#pragma unroll
            for (int i = 0; i < 4; i++) {
                int c = rb + i * 32;
                *(bf16x8*)&Wh[c * LDSTR + ks] = *(const bf16x8*)&Wth[(size_t)c * D + k0 + ks];
                *(bf16x8*)&Wl[c * LDSTR + ks] = *(const bf16x8*)&Wtl[(size_t)c * D + k0 + ks];
            }
        }
        __syncthreads();
#pragma unroll
        for (int ks = 0; ks < BK; ks += 32) {
            bf16x8 ah = *(const bf16x8*)&Xh[(wv * 16 + m) * LDSTR + ks + q * 8];
            bf16x8 al = *(const bf16x8*)&Xl[(wv * 16 + m) * LDSTR + ks + q * 8];
#pragma unroll
            for (int c = 0; c < 8; c++) {
                bf16x8 bh = *(const bf16x8*)&Wh[(c * 16 + m) * LDSTR + ks + q * 8];
                bf16x8 bl = *(const bf16x8*)&Wl[(c * 16 + m) * LDSTR + ks + q * 8];
                acc[c] = __builtin_amdgcn_mfma_f32_16x16x32_bf16(ah, bh, acc[c], 0, 0, 0);
                acc[c] = __builtin_amdgcn_mfma_f32_16x16x32_bf16(al, bh, acc[c], 0, 0, 0);
                acc[c] = __builtin_amdgcn_mfma_f32_16x16x32_bf16(ah, bl, acc[c], 0, 0, 0);
            }
        }
    }
    // epilogue: D layout col=lane&15, row=(lane>>4)*4+reg
#pragma unroll
    for (int c = 0; c < 8; c++)
#pragma unroll
        for (int r = 0; r < 4; r++) {
            int grow = rowbase + wv * 16 + q * 4 + r;
            if (grow < N) Y[(size_t)grow * H + c * 16 + m] = acc[c][r];
        }
}

// ---------------- aggregation ----------------
// Out[i] = act( norm_d[i] * (Y[i] + sum_{e:dst=i} Y[src_e]) + b )
__global__ __launch_bounds__(256) void aggK(const float* __restrict__ Y,
                                            const int* __restrict__ rowptr,
                                            const int* __restrict__ esrc,
                                            const float* __restrict__ norm_d,
                                            const float* __restrict__ bias,
                                            float* __restrict__ Out, int N, int relu) {
    int wave = threadIdx.x >> 6;
    int lane = threadIdx.x & 63;
    int node = blockIdx.x * 4 + wave;
    if (node >= N) return;
    int beg = rowptr[node], end = rowptr[node + 1];
    const float2* y2 = (const float2*)Y;
    float2 acc = y2[(size_t)node * 64 + lane];  // self-loop
    int j = beg;
    for (; j + 1 < end; j += 2) {
        int s0 = esrc[j], s1 = esrc[j + 1];
        float2 v0 = y2[(size_t)s0 * 64 + lane];
        float2 v1 = y2[(size_t)s1 * 64 + lane];
        acc.x += v0.x + v1.x;
        acc.y += v0.y + v1.y;
    }
    if (j < end) {
        int s0 = esrc[j];
        float2 v0 = y2[(size_t)s0 * 64 + lane];
        acc.x += v0.x;
        acc.y += v0.y;
    }
    float nd = norm_d[node];
    float2 b = ((const float2*)bias)[lane];
    float ox = fmaf(acc.x, nd, b.x);
    float oy = fmaf(acc.y, nd, b.y);
    if (relu) { ox = ox > 0.f ? ox : 0.f; oy = oy > 0.f ? oy : 0.f; }
    ((float2*)Out)[(size_t)node * 64 + lane] = make_float2(ox, oy);
}

// ---------------- host ----------------

static inline int ceil_div(int a, int b) { return (a + b - 1) / b; }

struct TypeBufs {
    int *deg_out, *deg_in, *fill, *rowptr, *bsum, *esrc;
    float *norm_s, *norm_d, *y, *h;
    bf16 *wth0, *wtl0, *wth1, *wtl1;
};

extern "C" void kernel_launch(void* const* d_in, const int* in_sizes, int n_in,
                              void* d_out, int out_size, void* d_ws, size_t ws_size,
                              hipStream_t stream) {
    (void)n_in; (void)out_size; (void)ws_size;
    const float* feat_a = (const float*)d_in[0];
    const float* feat_b = (const float*)d_in[1];
    const int* src_a = (const int*)d_in[2];
    const int* dst_a = (const int*)d_in[3];
    const int* src_b = (const int*)d_in[4];
    const int* dst_b = (const int*)d_in[5];
    const float* Wa0 = (const float*)d_in[6];
    const float* ba0 = (const float*)d_in[7];
    const float* Wa1 = (const float*)d_in[8];
    const float* ba1 = (const float*)d_in[9];
    const float* Wb0 = (const float*)d_in[10];
    const float* bb0 = (const float*)d_in[11];
    const float* Wb1 = (const float*)d_in[12];
    const float* bb1 = (const float*)d_in[13];

    const int DA = in_sizes[6] / H;   // 256
    const int DB = in_sizes[10] / H;  // 128
    const int NA = in_sizes[0] / DA;  // 50000
    const int NB = in_sizes[1] / DB;  // 30000
    const int EA = in_sizes[2];       // 600000
    const int EB = in_sizes[4];       // 300000

    char* w = (char*)d_ws;
    auto carve = [&](size_t bytes) {
        void* p = (void*)w;
        w += (bytes + 255) & ~(size_t)255;
        return p;
    };
    auto carve_type = [&](int N, int E, int D) {
        TypeBufs tb;
        tb.deg_out = (int*)carve((size_t)N * 4);
        tb.deg_in  = (int*)carve((size_t)N * 4);
        tb.fill    = (int*)carve((size_t)N * 4);
        tb.rowptr  = (int*)carve(((size_t)N + 1) * 4);
        tb.bsum    = (int*)carve(64 * 4);
        tb.esrc    = (int*)carve((size_t)E * 4);
        tb.norm_s  = (float*)carve((size_t)N * 4);
        tb.norm_d  = (float*)carve((size_t)N * 4);
        tb.y       = (float*)carve((size_t)N * H * 4);
        tb.h       = (float*)carve((size_t)N * H * 4);
        tb.wth0    = (bf16*)carve((size_t)D * H * 2);
        tb.wtl0    = (bf16*)carve((size_t)D * H * 2);
        tb.wth1    = (bf16*)carve((size_t)H * H * 2);
        tb.wtl1    = (bf16*)carve((size_t)H * H * 2);
        return tb;
    };
    TypeBufs A = carve_type(NA, EA, DA);
    TypeBufs B = carve_type(NB, EB, DB);

    float* out_a = (float*)d_out;
    float* out_b = out_a + (size_t)NA * H;

    auto run_type = [&](const TypeBufs& tb, const float* feat, const int* src, const int* dst,
                        const float* W0, const float* b0, const float* W1, const float* b1,
                        int N, int E, int D, float* out) {
        // graph prep
        initK<<<ceil_div(N, 256), 256, 0, stream>>>(tb.deg_out, tb.deg_in, tb.fill, N);
        degK<<<ceil_div(E, 256), 256, 0, stream>>>(src, dst, tb.deg_out, tb.deg_in, E);
        normK<<<ceil_div(N, 256), 256, 0, stream>>>(tb.deg_out, tb.deg_in, tb.norm_s, tb.norm_d, N);
        int nb = ceil_div(N, 1024);
        scan1<<<nb, 256, 0, stream>>>(tb.deg_in, tb.rowptr, tb.bsum, N);
        scan2<<<1, 64, 0, stream>>>(tb.bsum, nb);
        scan3<<<ceil_div(N, 256), 256, 0, stream>>>(tb.rowptr, tb.bsum, N, E);
        fillK<<<ceil_div(E, 256), 256, 0, stream>>>(src, dst, tb.rowptr, tb.fill, tb.esrc, E);
        // weight prep
        wconv<<<D, H, 0, stream>>>(W0, tb.wth0, tb.wtl0, D);
        wconv<<<H, H, 0, stream>>>(W1, tb.wth1, tb.wtl1, H);
        // layer 0
        gemm_mfma<<<ceil_div(N, 64), 256, 0, stream>>>(feat, tb.wth0, tb.wtl0, tb.norm_s, tb.y, N, D);
        aggK<<<ceil_div(N, 4), 256, 0, stream>>>(tb.y, tb.rowptr, tb.esrc, tb.norm_d, b0, tb.h, N, 1);
        // layer 1
        gemm_mfma<<<ceil_div(N, 64), 256, 0, stream>>>(tb.h, tb.wth1, tb.wtl1, tb.norm_s, tb.y, N, H);
        aggK<<<ceil_div(N, 4), 256, 0, stream>>>(tb.y, tb.rowptr, tb.esrc, tb.norm_d, b1, out, N, 0);
    };

    run_type(A, feat_a, src_a, dst_a, Wa0, ba0, Wa1, ba1, NA, EA, DA, out_a);
    run_type(B, feat_b, src_b, dst_b, Wb0, bb0, Wb1, bb1, NB, EB, DB, out_b);
}

// Round 3
// 400.301 us; speedup vs baseline: 1.6852x; 1.2699x over previous
//
#include <hip/hip_runtime.h>
#include <hip/hip_bf16.h>

#define H 128
#define BK 64
#define LDSTR 72  // LDS row stride (bf16 elems): 144B -> 2-way bank alias (free)

typedef __bf16 bf16;
typedef _Float16 f16;
typedef __attribute__((ext_vector_type(8))) __bf16 bf16x8;
typedef __attribute__((ext_vector_type(4))) __bf16 bf16x4;
typedef __attribute__((ext_vector_type(2))) _Float16 f16x2;
typedef __attribute__((ext_vector_type(4))) float floatx4;

// ---------------- graph preprocessing (merged A+B) ----------------

__global__ void initAB(int* doA, int* diA, int* fA, int NA,
                       int* doB, int* diB, int* fB, int NB) {
    int i = blockIdx.x * 256 + threadIdx.x;
    if (i < NA) { doA[i] = 1; diA[i] = 1; fA[i] = 0; }
    else if (i < NA + NB) { int j = i - NA; doB[j] = 1; diB[j] = 1; fB[j] = 0; }
}

__global__ void degAB(const int* __restrict__ sA, const int* __restrict__ dA,
                      int* doA, int* diA, int EA,
                      const int* __restrict__ sB, const int* __restrict__ dB,
                      int* doB, int* diB, int EB) {
    int e = blockIdx.x * 256 + threadIdx.x;
    if (e < EA) {
        atomicAdd(&doA[sA[e]], 1);
        atomicAdd(&diA[dA[e]], 1);
    } else if (e < EA + EB) {
        int f = e - EA;
        atomicAdd(&doB[sB[f]], 1);
        atomicAdd(&diB[dB[f]], 1);
    }
}

// exclusive scan of (deg_in-1): phase 1, 1024 elems/block, block-partitioned A|B
__global__ __launch_bounds__(256) void scan1AB(const int* __restrict__ diA, int* rpA,
                                               int* bsA, int nA, int nbA,
                                               const int* __restrict__ diB, int* rpB,
                                               int* bsB, int nB) {
    const int* di; int* rp; int* bs; int n, blk;
    if ((int)blockIdx.x < nbA) { di = diA; rp = rpA; bs = bsA; n = nA; blk = blockIdx.x; }
    else { di = diB; rp = rpB; bs = bsB; n = nB; blk = blockIdx.x - nbA; }
    __shared__ int sh[256];
    int t = threadIdx.x;
    int base = blk * 1024 + t * 4;
    int v[4];
#pragma unroll
    for (int i = 0; i < 4; i++) {
        int idx = base + i;
        v[i] = (idx < n) ? (di[idx] - 1) : 0;
    }
    int s = v[0] + v[1] + v[2] + v[3];
    sh[t] = s;
    __syncthreads();
    for (int off = 1; off < 256; off <<= 1) {
        int x = (t >= off) ? sh[t - off] : 0;
        __syncthreads();
        sh[t] += x;
        __syncthreads();
    }
    int run = sh[t] - s;
#pragma unroll
    for (int i = 0; i < 4; i++) {
        int idx = base + i;
        if (idx < n) rp[idx] = run;
        run += v[i];
    }
    if (t == 255) bs[blk] = sh[255];
}

// phase 2: wave 0 scans A's block sums, wave 1 scans B's
__global__ void scan2AB(int* bsA, int nbA, int* bsB, int nbB) {
    int w = threadIdx.x >> 6, lane = threadIdx.x & 63;
    int* bs = w ? bsB : bsA;
    int nb = w ? nbB : nbA;
    int v = (lane < nb) ? bs[lane] : 0;
    int orig = v;
    for (int off = 1; off < 64; off <<= 1) {
        int x = __shfl_up(v, off, 64);
        if (lane >= off) v += x;
    }
    if (lane < nb) bs[lane] = v - orig;
}

// phase 3 + norms
__global__ void scan3AB(int* rpA, const int* __restrict__ bsA,
                        const int* __restrict__ doA, const int* __restrict__ diA,
                        float* nsA, float* ndA, int NA, int EA,
                        int* rpB, const int* __restrict__ bsB,
                        const int* __restrict__ doB, const int* __restrict__ diB,
                        float* nsB, float* ndB, int NB, int EB) {
    int i = blockIdx.x * 256 + threadIdx.x;
    if (i < NA) {
        rpA[i] += bsA[i >> 10];
        nsA[i] = rsqrtf((float)doA[i]);
        ndA[i] = rsqrtf((float)diA[i]);
        if (i == 0) { rpA[NA] = EA; rpB[NB] = EB; }
    } else if (i < NA + NB) {
        int j = i - NA;
        rpB[j] += bsB[j >> 10];
        nsB[j] = rsqrtf((float)doB[j]);
        ndB[j] = rsqrtf((float)diB[j]);
    }
}

__global__ void fillAB(const int* __restrict__ sA, const int* __restrict__ dA,
                       const int* __restrict__ rpA, int* fA, int* esA, int EA,
                       const int* __restrict__ sB, const int* __restrict__ dB,
                       const int* __restrict__ rpB, int* fB, int* esB, int EB) {
    int e = blockIdx.x * 256 + threadIdx.x;
    if (e < EA) {
        int d = dA[e];
        esA[rpA[d] + atomicAdd(&fA[d], 1)] = sA[e];
    } else if (e < EA + EB) {
        int f = e - EA;
        int d = dB[f];
        esB[rpB[d] + atomicAdd(&fB[d], 1)] = sB[f];
    }
}

// ---------------- weight prep: transpose + split-bf16, all 4 matrices ----------------
__global__ void wconvAB(const float* __restrict__ Wa0, bf16* tha0, bf16* tla0,
                        const float* __restrict__ Wa1, bf16* tha1, bf16* tla1,
                        const float* __restrict__ Wb0, bf16* thb0, bf16* tlb0,
                        const float* __restrict__ Wb1, bf16* thb1, bf16* tlb1, int DA) {
    int b = blockIdx.x;
    const float* W; bf16 *th, *tl; int k, D;
    if (b < DA) { W = Wa0; th = tha0; tl = tla0; k = b; D = DA; }
    else if (b < DA + H) { W = Wa1; th = tha1; tl = tla1; k = b - DA; D = H; }
    else if (b < DA + 2 * H) { W = Wb0; th = thb0; tl = tlb0; k = b - DA - H; D = H; }
    else { W = Wb1; th = thb1; tl = tlb1; k = b - DA - 2 * H; D = H; }
    int c = threadIdx.x;
    float v = W[(size_t)k * H + c];
    bf16 h = (bf16)v;
    th[(size_t)c * D + k] = h;
    tl[(size_t)c * D + k] = (bf16)(v - (float)h);
}

// ---------------- MFMA GEMM (merged A+B): Y = f16( (X * norm_s) @ W ) ----------------
__global__ __launch_bounds__(256) void gemmAB(
    const float* __restrict__ XA, const bf16* __restrict__ WthA, const bf16* __restrict__ WtlA,
    const float* __restrict__ nsA, f16* __restrict__ YA, int NA, int DA, int nblkA,
    const float* __restrict__ XB, const bf16* __restrict__ WthB, const bf16* __restrict__ WtlB,
    const float* __restrict__ nsB, f16* __restrict__ YB, int NB, int DB) {
    const float* X; const bf16 *Wth, *Wtl; const float* ns; f16* Y; int N, D, bid;
    if ((int)blockIdx.x < nblkA) {
        X = XA; Wth = WthA; Wtl = WtlA; ns = nsA; Y = YA; N = NA; D = DA; bid = blockIdx.x;
    } else {
        X = XB; Wth = WthB; Wtl = WtlB; ns = nsB; Y = YB; N = NB; D = DB; bid = blockIdx.x - nblkA;
    }
    __shared__ bf16 Xh[64 * LDSTR], Xl[64 * LDSTR];
    __shared__ bf16 Wh[128 * LDSTR], Wl[128 * LDSTR];
    int t = threadIdx.x;
    int wv = t >> 6, lane = t & 63;
    int m = lane & 15, q = lane >> 4;
    int rowbase = bid * 64;

    floatx4 acc[8];
#pragma unroll
    for (int c = 0; c < 8; c++) acc[c] = (floatx4)(0.f);

    for (int k0 = 0; k0 < D; k0 += BK) {
        __syncthreads();
        {   // stage X chunk: 64 rows x 64 k, fold norm_s, split hi/lo
            int kq = (t & 15) * 4;
#pragma unroll
            for (int i = 0; i < 4; i++) {
                int r = (t >> 4) + i * 16;
                int grow = rowbase + r;
                float4 v = make_float4(0.f, 0.f, 0.f, 0.f);
                float nsv = 0.f;
                if (grow < N) {
                    v = *(const float4*)(X + (size_t)grow * D + k0 + kq);
                    nsv = ns[grow];
                }
                float xs4[4] = {v.x * nsv, v.y * nsv, v.z * nsv, v.w * nsv};
                bf16x4 hv, lv;
#pragma unroll
                for (int j = 0; j < 4; j++) {
                    bf16 h = (bf16)xs4[j];
                    hv[j] = h;
                    lv[j] = (bf16)(xs4[j] - (float)h);
                }
                *(bf16x4*)&Xh[r * LDSTR + kq] = hv;
                *(bf16x4*)&Xl[r * LDSTR + kq] = lv;
            }
        }
        {   // stage W chunk: 128 c x 64 k
            int ks = (t & 7) * 8;
            int rb = t >> 3;
#pragma unroll
            for (int i = 0; i < 4; i++) {
                int c = rb + i * 32;
                *(bf16x8*)&Wh[c * LDSTR + ks] = *(const bf16x8*)&Wth[(size_t)c * D + k0 + ks];
                *(bf16x8*)&Wl[c * LDSTR + ks] = *(const bf16x8*)&Wtl[(size_t)c * D + k0 + ks];
            }
        }
        __syncthreads();
#pragma unroll
        for (int ks = 0; ks < BK; ks += 32) {
            bf16x8 ah = *(const bf16x8*)&Xh[(wv * 16 + m) * LDSTR + ks + q * 8];
            bf16x8 al = *(const bf16x8*)&Xl[(wv * 16 + m) * LDSTR + ks + q * 8];
#pragma unroll
            for (int c = 0; c < 8; c++) {
                bf16x8 bh = *(const bf16x8*)&Wh[(c * 16 + m) * LDSTR + ks + q * 8];
                bf16x8 bl = *(const bf16x8*)&Wl[(c * 16 + m) * LDSTR + ks + q * 8];
                acc[c] = __builtin_amdgcn_mfma_f32_16x16x32_bf16(ah, bh, acc[c], 0, 0, 0);
                acc[c] = __builtin_amdgcn_mfma_f32_16x16x32_bf16(al, bh, acc[c], 0, 0, 0);
                acc[c] = __builtin_amdgcn_mfma_f32_16x16x32_bf16(ah, bl, acc[c], 0, 0, 0);
            }
        }
    }
    // D layout: col=lane&15, row=(lane>>4)*4+reg ; store as fp16
#pragma unroll
    for (int c = 0; c < 8; c++)
#pragma unroll
        for (int r = 0; r < 4; r++) {
            int grow = rowbase + wv * 16 + q * 4 + r;
            if (grow < N) Y[(size_t)grow * H + c * 16 + m] = (f16)acc[c][r];
        }
}

// ---------------- aggregation (merged A+B), fp16 gather, fp32 accumulate ----------------
__global__ __launch_bounds__(256) void aggAB(
    const f16* __restrict__ YA, const int* __restrict__ rpA, const int* __restrict__ esA,
    const float* __restrict__ ndA, const float* __restrict__ bA, float* __restrict__ OA,
    int nA4, int NA,
    const f16* __restrict__ YB, const int* __restrict__ rpB, const int* __restrict__ esB,
    const float* __restrict__ ndB, const float* __restrict__ bB, float* __restrict__ OB,
    int NB, int relu) {
    const f16* Y; const int *rp, *es; const float *nd, *bias; float* Out; int N, blk;
    if ((int)blockIdx.x < nA4) {
        Y = YA; rp = rpA; es = esA; nd = ndA; bias = bA; Out = OA; N = NA; blk = blockIdx.x;
    } else {
        Y = YB; rp = rpB; es = esB; nd = ndB; bias = bB; Out = OB; N = NB; blk = blockIdx.x - nA4;
    }
    int wave = threadIdx.x >> 6;
    int lane = threadIdx.x & 63;
    int node = blk * 4 + wave;
    if (node >= N) return;
    int beg = rp[node], end = rp[node + 1];
    const f16x2* y2 = (const f16x2*)Y;
    f16x2 sv = y2[(size_t)node * 64 + lane];  // self-loop
    float ax = (float)sv[0], ay = (float)sv[1];
    int j = beg;
    for (; j + 3 < end; j += 4) {
        int s0 = es[j], s1 = es[j + 1], s2 = es[j + 2], s3 = es[j + 3];
        f16x2 v0 = y2[(size_t)s0 * 64 + lane];
        f16x2 v1 = y2[(size_t)s1 * 64 + lane];
        f16x2 v2 = y2[(size_t)s2 * 64 + lane];
        f16x2 v3 = y2[(size_t)s3 * 64 + lane];
        ax += (float)v0[0] + (float)v1[0] + (float)v2[0] + (float)v3[0];
        ay += (float)v0[1] + (float)v1[1] + (float)v2[1] + (float)v3[1];
    }
    for (; j < end; j++) {
        f16x2 v0 = y2[(size_t)es[j] * 64 + lane];
        ax += (float)v0[0];
        ay += (float)v0[1];
    }
    float ndv = nd[node];
    float2 b = ((const float2*)bias)[lane];
    float ox = fmaf(ax, ndv, b.x);
    float oy = fmaf(ay, ndv, b.y);
    if (relu) { ox = ox > 0.f ? ox : 0.f; oy = oy > 0.f ? oy : 0.f; }
    ((float2*)Out)[(size_t)node * 64 + lane] = make_float2(ox, oy);
}

// ---------------- host ----------------

static inline int ceil_div(int a, int b) { return (a + b - 1) / b; }

struct TypeBufs {
    int *deg_out, *deg_in, *fill, *rowptr, *bsum, *esrc;
    float *norm_s, *norm_d, *h;
    f16* y;
    bf16 *wth0, *wtl0, *wth1, *wtl1;
};

extern "C" void kernel_launch(void* const* d_in, const int* in_sizes, int n_in,
                              void* d_out, int out_size, void* d_ws, size_t ws_size,
                              hipStream_t stream) {
    (void)n_in; (void)out_size; (void)ws_size;
    const float* feat_a = (const float*)d_in[0];
    const float* feat_b = (const float*)d_in[1];
    const int* src_a = (const int*)d_in[2];
    const int* dst_a = (const int*)d_in[3];
    const int* src_b = (const int*)d_in[4];
    const int* dst_b = (const int*)d_in[5];
    const float* Wa0 = (const float*)d_in[6];
    const float* ba0 = (const float*)d_in[7];
    const float* Wa1 = (const float*)d_in[8];
    const float* ba1 = (const float*)d_in[9];
    const float* Wb0 = (const float*)d_in[10];
    const float* bb0 = (const float*)d_in[11];
    const float* Wb1 = (const float*)d_in[12];
    const float* bb1 = (const float*)d_in[13];

    const int DA = in_sizes[6] / H;   // 256
    const int DB = in_sizes[10] / H;  // 128
    const int NA = in_sizes[0] / DA;  // 50000
    const int NB = in_sizes[1] / DB;  // 30000
    const int EA = in_sizes[2];       // 600000
    const int EB = in_sizes[4];       // 300000

    char* w = (char*)d_ws;
    auto carve = [&](size_t bytes) {
        void* p = (void*)w;
        w += (bytes + 255) & ~(size_t)255;
        return p;
    };
    auto carve_type = [&](int N, int E, int D) {
        TypeBufs tb;
        tb.deg_out = (int*)carve((size_t)N * 4);
        tb.deg_in  = (int*)carve((size_t)N * 4);
        tb.fill    = (int*)carve((size_t)N * 4);
        tb.rowptr  = (int*)carve(((size_t)N + 1) * 4);
        tb.bsum    = (int*)carve(64 * 4);
        tb.esrc    = (int*)carve((size_t)E * 4);
        tb.norm_s  = (float*)carve((size_t)N * 4);
        tb.norm_d  = (float*)carve((size_t)N * 4);
        tb.h       = (float*)carve((size_t)N * H * 4);
        tb.y       = (f16*)carve((size_t)N * H * 2);
        tb.wth0    = (bf16*)carve((size_t)D * H * 2);
        tb.wtl0    = (bf16*)carve((size_t)D * H * 2);
        tb.wth1    = (bf16*)carve((size_t)H * H * 2);
        tb.wtl1    = (bf16*)carve((size_t)H * H * 2);
        return tb;
    };
    TypeBufs A = carve_type(NA, EA, DA);
    TypeBufs B = carve_type(NB, EB, DB);

    float* out_a = (float*)d_out;
    float* out_b = out_a + (size_t)NA * H;

    int nbA = ceil_div(NA, 1024), nbB = ceil_div(NB, 1024);
    int nblkA = ceil_div(NA, 64), nblkB = ceil_div(NB, 64);
    int nA4 = ceil_div(NA, 4), nB4 = ceil_div(NB, 4);

    initAB<<<ceil_div(NA + NB, 256), 256, 0, stream>>>(A.deg_out, A.deg_in, A.fill, NA,
                                                       B.deg_out, B.deg_in, B.fill, NB);
    degAB<<<ceil_div(EA + EB, 256), 256, 0, stream>>>(src_a, dst_a, A.deg_out, A.deg_in, EA,
                                                      src_b, dst_b, B.deg_out, B.deg_in, EB);
    scan1AB<<<nbA + nbB, 256, 0, stream>>>(A.deg_in, A.rowptr, A.bsum, NA, nbA,
                                           B.deg_in, B.rowptr, B.bsum, NB);
    scan2AB<<<1, 128, 0, stream>>>(A.bsum, nbA, B.bsum, nbB);
    scan3AB<<<ceil_div(NA + NB, 256), 256, 0, stream>>>(
        A.rowptr, A.bsum, A.deg_out, A.deg_in, A.norm_s, A.norm_d, NA, EA,
        B.rowptr, B.bsum, B.deg_out, B.deg_in, B.norm_s, B.norm_d, NB, EB);
    fillAB<<<ceil_div(EA + EB, 256), 256, 0, stream>>>(
        src_a, dst_a, A.rowptr, A.fill, A.esrc, EA,
        src_b, dst_b, B.rowptr, B.fill, B.esrc, EB);
    wconvAB<<<DA + 3 * H, H, 0, stream>>>(Wa0, A.wth0, A.wtl0, Wa1, A.wth1, A.wtl1,
                                          Wb0, B.wth0, B.wtl0, Wb1, B.wth1, B.wtl1, DA);
    // layer 0
    gemmAB<<<nblkA + nblkB, 256, 0, stream>>>(
        feat_a, A.wth0, A.wtl0, A.norm_s, A.y, NA, DA, nblkA,
        feat_b, B.wth0, B.wtl0, B.norm_s, B.y, NB, DB);
    aggAB<<<nA4 + nB4, 256, 0, stream>>>(
        A.y, A.rowptr, A.esrc, A.norm_d, ba0, A.h, nA4, NA,
        B.y, B.rowptr, B.esrc, B.norm_d, bb0, B.h, NB, 1);
    // layer 1
    gemmAB<<<nblkA + nblkB, 256, 0, stream>>>(
        A.h, A.wth1, A.wtl1, A.norm_s, A.y, NA, H, nblkA,
        B.h, B.wth1, B.wtl1, B.norm_s, B.y, NB, H);
    aggAB<<<nA4 + nB4, 256, 0, stream>>>(
        A.y, A.rowptr, A.esrc, A.norm_d, ba1, out_a, nA4, NA,
        B.y, B.rowptr, B.esrc, B.norm_d, bb1, out_b, NB, 0);
}

// Round 4
// 386.484 us; speedup vs baseline: 1.7454x; 1.0358x over previous
//
#include <hip/hip_runtime.h>
#include <hip/hip_bf16.h>

#define H 128
#define BK 64
#define LDSTR 72   // LDS row stride (bf16 elems): 144B -> 2-way bank alias (free)

#define EPB 8192        // edges per block, coarse passes
#define BUCK_BITS 8
#define BUCK 256        // nodes per bucket
#define CHN 25000       // nodes per deg-out chunk (16-bit packed counters, 50KB LDS)
#define SLOTS 12500
#define SLA 24          // edge slices per chunk, type A
#define SLB 16

typedef __bf16 bf16;
typedef _Float16 f16;
typedef unsigned int u32;
typedef __attribute__((ext_vector_type(8))) __bf16 bf16x8;
typedef __attribute__((ext_vector_type(4))) __bf16 bf16x4;
typedef __attribute__((ext_vector_type(2))) _Float16 f16x2;
typedef __attribute__((ext_vector_type(4))) float floatx4;

// ---------------- P1: coarse histogram by dst>>8 (LDS atomics only) ----------------
__global__ __launch_bounds__(256) void p1K(
    const int* __restrict__ dA, int* __restrict__ chA, int EA, int nblkA, int nbinsA,
    const int* __restrict__ dB, int* __restrict__ chB, int EB, int nblkB, int nbinsB) {
    __shared__ int bins[BUCK];
    const int* dst; int* ch; int E, nblk, nbins, blk;
    if ((int)blockIdx.x < nblkA) { dst = dA; ch = chA; E = EA; nblk = nblkA; nbins = nbinsA; blk = blockIdx.x; }
    else { dst = dB; ch = chB; E = EB; nblk = nblkB; nbins = nbinsB; blk = blockIdx.x - nblkA; }
    int t = threadIdx.x;
    bins[t] = 0;
    __syncthreads();
    int e0 = blk * EPB, e1 = min(E, e0 + EPB);
    for (int e = e0 + t; e < e1; e += 256) atomicAdd(&bins[dst[e] >> BUCK_BITS], 1);
    __syncthreads();
    for (int b = t; b < nbins; b += 256) ch[b * nblk + blk] = bins[b];
}

// ---------------- P2: exclusive scan of (bucket x block) matrix, one block/type ----------------
__global__ __launch_bounds__(256) void p2K(
    int* chA, int LA, int* bbA, int nbinsA, int nblkA, int EA, int* rpA, int NA,
    int* chB, int LB, int* bbB, int nbinsB, int nblkB, int EB, int* rpB, int NB) {
    __shared__ int sh[256];
    int* ch; int L; int* bb; int nbins, nblk, E; int* rp; int N;
    if (blockIdx.x == 0) { ch = chA; L = LA; bb = bbA; nbins = nbinsA; nblk = nblkA; E = EA; rp = rpA; N = NA; }
    else { ch = chB; L = LB; bb = bbB; nbins = nbinsB; nblk = nblkB; E = EB; rp = rpB; N = NB; }
    int t = threadIdx.x;
    int per = (L + 255) >> 8;
    int lo = t * per, hi = min(lo + per, L);
    int s = 0;
    for (int i = lo; i < hi; i++) s += ch[i];
    sh[t] = s;
    __syncthreads();
    for (int off = 1; off < 256; off <<= 1) {
        int x = (t >= off) ? sh[t - off] : 0;
        __syncthreads();
        sh[t] += x;
        __syncthreads();
    }
    int run = sh[t] - s;
    for (int i = lo; i < hi; i++) { int v = ch[i]; ch[i] = run; run += v; }
    __syncthreads();
    for (int b = t; b <= nbins; b += 256) bb[b] = (b < nbins) ? ch[b * nblk] : E;
    if (t == 0) rp[N] = E;
}

// ---------------- P3: scatter edges to bucket-ordered array (plain stores) ----------------
__global__ __launch_bounds__(256) void p3K(
    const int* __restrict__ sA, const int* __restrict__ dA, const int* __restrict__ chA,
    u32* __restrict__ binA, int EA, int nblkA, int nbinsA,
    const int* __restrict__ sB, const int* __restrict__ dB, const int* __restrict__ chB,
    u32* __restrict__ binB, int EB, int nblkB, int nbinsB) {
    __shared__ int bins[BUCK];
    __shared__ int off[BUCK];
    const int *src, *dst; const int* ch; u32* bin; int E, nblk, nbins, blk;
    if ((int)blockIdx.x < nblkA) {
        src = sA; dst = dA; ch = chA; bin = binA; E = EA; nblk = nblkA; nbins = nbinsA; blk = blockIdx.x;
    } else {
        src = sB; dst = dB; ch = chB; bin = binB; E = EB; nblk = nblkB; nbins = nbinsB; blk = blockIdx.x - nblkA;
    }
    int t = threadIdx.x;
    bins[t] = 0;
    if (t < nbins) off[t] = ch[t * nblk + blk];
    __syncthreads();
    int e0 = blk * EPB, e1 = min(E, e0 + EPB);
    for (int e = e0 + t; e < e1; e += 256) {
        int d = dst[e], s = src[e];
        int b = d >> BUCK_BITS;
        int r = atomicAdd(&bins[b], 1);
        bin[off[b] + r] = (u32)s | ((u32)(d & (BUCK - 1)) << 16);
    }
}

// ---------------- P4: per-bucket fine pass -> norm_d, rowptr, esrc ----------------
__global__ __launch_bounds__(256) void p4K(
    const u32* __restrict__ binA, const int* __restrict__ bbA, int nbinsA,
    int* __restrict__ rpA, float* __restrict__ ndA, int* __restrict__ esA, int NA,
    const u32* __restrict__ binB, const int* __restrict__ bbB, int nbinsB,
    int* __restrict__ rpB, float* __restrict__ ndB, int* __restrict__ esB, int NB) {
    __shared__ int cnt[BUCK], pos[BUCK], fill[BUCK];
    const u32* bin; const int* bb; int* rp; float* nd; int* es; int N, blk;
    if ((int)blockIdx.x < nbinsA) {
        bin = binA; bb = bbA; rp = rpA; nd = ndA; es = esA; N = NA; blk = blockIdx.x;
    } else {
        bin = binB; bb = bbB; rp = rpB; nd = ndB; es = esB; N = NB; blk = blockIdx.x - nbinsA;
    }
    int t = threadIdx.x;
    int e0 = bb[blk], e1 = bb[blk + 1];
    cnt[t] = 0; fill[t] = 0;
    __syncthreads();
    for (int e = e0 + t; e < e1; e += 256) atomicAdd(&cnt[(bin[e] >> 16) & 255], 1);
    __syncthreads();
    int c = cnt[t];
    int node = (blk << BUCK_BITS) + t;
    if (node < N) nd[node] = rsqrtf((float)(c + 1));
    pos[t] = c;
    __syncthreads();
    for (int off = 1; off < 256; off <<= 1) {
        int x = (t >= off) ? pos[t - off] : 0;
        __syncthreads();
        pos[t] += x;
        __syncthreads();
    }
    int start = e0 + pos[t] - c;   // exclusive prefix -> absolute CSR start
    pos[t] = start;                // own-element overwrite, no cross-read until barrier
    if (node < N) rp[node] = start;
    __syncthreads();
    for (int e = e0 + t; e < e1; e += 256) {
        u32 w = bin[e];
        int i = (w >> 16) & 255;
        int r = atomicAdd(&fill[i], 1);
        es[pos[i] + r] = (int)(w & 0xFFFFu);
    }
}

// ---------------- deg_out: chunked LDS histogram, packed 16-bit counters ----------------
__global__ __launch_bounds__(256) void doHistK(
    const int* __restrict__ sA, int EA, u32* __restrict__ pA, int NA,
    const int* __restrict__ sB, int EB, u32* __restrict__ pB, int NB) {
    __shared__ u32 pk[SLOTS];
    const int* src; u32* part; int E, sl, chunk, g;
    int nchA = (NA + CHN - 1) / CHN;
    int bid = blockIdx.x;
    int blocksA = nchA * SLA;
    if (bid < blocksA) { src = sA; part = pA; E = EA; sl = SLA; chunk = bid / SLA; g = bid % SLA; }
    else { bid -= blocksA; src = sB; part = pB; E = EB; sl = SLB; chunk = bid / SLB; g = bid % SLB; }
    int t = threadIdx.x;
    for (int i = t; i < SLOTS; i += 256) pk[i] = 0;
    __syncthreads();
    int lo_node = chunk * CHN;
    int per = (E + sl - 1) / sl;
    int e0 = g * per, e1 = min(E, e0 + per);
    for (int e = e0 + t; e < e1; e += 256) {
        int s = src[e] - lo_node;
        if ((unsigned)s < (unsigned)CHN) atomicAdd(&pk[s >> 1], 1u << ((s & 1) << 4));
    }
    __syncthreads();
    u32* dstp = part + (size_t)(chunk * sl + g) * SLOTS;
    for (int i = t; i < SLOTS; i += 256) dstp[i] = pk[i];
}

__global__ void doRedK(const u32* __restrict__ pA, float* __restrict__ nsA, int NA,
                       const u32* __restrict__ pB, float* __restrict__ nsB, int NB) {
    int i = blockIdx.x * 256 + threadIdx.x;
    const u32* part; float* ns; int sl, idx;
    if (i < NA) { part = pA; ns = nsA; sl = SLA; idx = i; }
    else if (i < NA + NB) { part = pB; ns = nsB; sl = SLB; idx = i - NA; }
    else return;
    int chunk = idx / CHN, local = idx % CHN;
    int slot = local >> 1, sh = (local & 1) << 4;
    u32 sum = 0;
    const u32* base = part + (size_t)chunk * sl * SLOTS + slot;
    for (int g = 0; g < sl; g++) sum += base[(size_t)g * SLOTS];
    int deg = (int)((sum >> sh) & 0xFFFFu);
    ns[idx] = rsqrtf((float)(deg + 1));
}

// ---------------- weight prep: transpose + split-bf16, all 4 matrices ----------------
__global__ void wconvAB(const float* __restrict__ Wa0, bf16* tha0, bf16* tla0,
                        const float* __restrict__ Wa1, bf16* tha1, bf16* tla1,
                        const float* __restrict__ Wb0, bf16* thb0, bf16* tlb0,
                        const float* __restrict__ Wb1, bf16* thb1, bf16* tlb1, int DA) {
    int b = blockIdx.x;
    const float* W; bf16 *th, *tl; int k, D;
    if (b < DA) { W = Wa0; th = tha0; tl = tla0; k = b; D = DA; }
    else if (b < DA + H) { W = Wa1; th = tha1; tl = tla1; k = b - DA; D = H; }
    else if (b < DA + 2 * H) { W = Wb0; th = thb0; tl = tlb0; k = b - DA - H; D = H; }
    else { W = Wb1; th = thb1; tl = tlb1; k = b - DA - 2 * H; D = H; }
    int c = threadIdx.x;
    float v = W[(size_t)k * H + c];
    bf16 h = (bf16)v;
    th[(size_t)c * D + k] = h;
    tl[(size_t)c * D + k] = (bf16)(v - (float)h);
}

// ---------------- MFMA GEMM (merged A+B): Y = f16( (X * norm_s) @ W ) ----------------
__global__ __launch_bounds__(256) void gemmAB(
    const float* __restrict__ XA, const bf16* __restrict__ WthA, const bf16* __restrict__ WtlA,
    const float* __restrict__ nsA, f16* __restrict__ YA, int NA, int DA, int nblkA,
    const float* __restrict__ XB, const bf16* __restrict__ WthB, const bf16* __restrict__ WtlB,
    const float* __restrict__ nsB, f16* __restrict__ YB, int NB, int DB) {
    const float* X; const bf16 *Wth, *Wtl; const float* ns; f16* Y; int N, D, bid;
    if ((int)blockIdx.x < nblkA) {
        X = XA; Wth = WthA; Wtl = WtlA; ns = nsA; Y = YA; N = NA; D = DA; bid = blockIdx.x;
    } else {
        X = XB; Wth = WthB; Wtl = WtlB; ns = nsB; Y = YB; N = NB; D = DB; bid = blockIdx.x - nblkA;
    }
    __shared__ bf16 Xh[64 * LDSTR], Xl[64 * LDSTR];
    __shared__ bf16 Wh[128 * LDSTR], Wl[128 * LDSTR];
    int t = threadIdx.x;
    int wv = t >> 6, lane = t & 63;
    int m = lane & 15, q = lane >> 4;
    int rowbase = bid * 64;

    floatx4 acc[8];
#pragma unroll
    for (int c = 0; c < 8; c++) acc[c] = (floatx4)(0.f);

    for (int k0 = 0; k0 < D; k0 += BK) {
        __syncthreads();
        {   // stage X chunk: 64 rows x 64 k, fold norm_s, split hi/lo
            int kq = (t & 15) * 4;
#pragma unroll
            for (int i = 0; i < 4; i++) {
                int r = (t >> 4) + i * 16;
                int grow = rowbase + r;
                float4 v = make_float4(0.f, 0.f, 0.f, 0.f);
                float nsv = 0.f;
                if (grow < N) {
                    v = *(const float4*)(X + (size_t)grow * D + k0 + kq);
                    nsv = ns[grow];
                }
                float xs4[4] = {v.x * nsv, v.y * nsv, v.z * nsv, v.w * nsv};
                bf16x4 hv, lv;
#pragma unroll
                for (int j = 0; j < 4; j++) {
                    bf16 h = (bf16)xs4[j];
                    hv[j] = h;
                    lv[j] = (bf16)(xs4[j] - (float)h);
                }
                *(bf16x4*)&Xh[r * LDSTR + kq] = hv;
                *(bf16x4*)&Xl[r * LDSTR + kq] = lv;
            }
        }
        {   // stage W chunk: 128 c x 64 k
            int ks = (t & 7) * 8;
            int rb = t >> 3;
#pragma unroll
            for (int i = 0; i < 4; i++) {
                int c = rb + i * 32;
                *(bf16x8*)&Wh[c * LDSTR + ks] = *(const bf16x8*)&Wth[(size_t)c * D + k0 + ks];
                *(bf16x8*)&Wl[c * LDSTR + ks] = *(const bf16x8*)&Wtl[(size_t)c * D + k0 + ks];
            }
        }
        __syncthreads();
#pragma unroll
        for (int ks = 0; ks < BK; ks += 32) {
            bf16x8 ah = *(const bf16x8*)&Xh[(wv * 16 + m) * LDSTR + ks + q * 8];
            bf16x8 al = *(const bf16x8*)&Xl[(wv * 16 + m) * LDSTR + ks + q * 8];
#pragma unroll
            for (int c = 0; c < 8; c++) {
                bf16x8 bh = *(const bf16x8*)&Wh[(c * 16 + m) * LDSTR + ks + q * 8];
                bf16x8 bl = *(const bf16x8*)&Wl[(c * 16 + m) * LDSTR + ks + q * 8];
                acc[c] = __builtin_amdgcn_mfma_f32_16x16x32_bf16(ah, bh, acc[c], 0, 0, 0);
                acc[c] = __builtin_amdgcn_mfma_f32_16x16x32_bf16(al, bh, acc[c], 0, 0, 0);
                acc[c] = __builtin_amdgcn_mfma_f32_16x16x32_bf16(ah, bl, acc[c], 0, 0, 0);
            }
        }
    }
    // D layout: col=lane&15, row=(lane>>4)*4+reg ; store as fp16
#pragma unroll
    for (int c = 0; c < 8; c++)
#pragma unroll
        for (int r = 0; r < 4; r++) {
            int grow = rowbase + wv * 16 + q * 4 + r;
            if (grow < N) Y[(size_t)grow * H + c * 16 + m] = (f16)acc[c][r];
        }
}

// ---------------- aggregation (merged A+B), fp16 gather, fp32 accumulate ----------------
__global__ __launch_bounds__(256) void aggAB(
    const f16* __restrict__ YA, const int* __restrict__ rpA, const int* __restrict__ esA,
    const float* __restrict__ ndA, const float* __restrict__ bA, float* __restrict__ OA,
    int nA4, int NA,
    const f16* __restrict__ YB, const int* __restrict__ rpB, const int* __restrict__ esB,
    const float* __restrict__ ndB, const float* __restrict__ bB, float* __restrict__ OB,
    int NB, int relu) {
    const f16* Y; const int *rp, *es; const float *nd, *bias; float* Out; int N, blk;
    if ((int)blockIdx.x < nA4) {
        Y = YA; rp = rpA; es = esA; nd = ndA; bias = bA; Out = OA; N = NA; blk = blockIdx.x;
    } else {
        Y = YB; rp = rpB; es = esB; nd = ndB; bias = bB; Out = OB; N = NB; blk = blockIdx.x - nA4;
    }
    int wave = threadIdx.x >> 6;
    int lane = threadIdx.x & 63;
    int node = blk * 4 + wave;
    if (node >= N) return;
    int beg = rp[node], end = rp[node + 1];
    const f16x2* y2 = (const f16x2*)Y;
    f16x2 sv = y2[(size_t)node * 64 + lane];  // self-loop
    float ax = (float)sv[0], ay = (float)sv[1];
    int j = beg;
    for (; j + 3 < end; j += 4) {
        int s0 = es[j], s1 = es[j + 1], s2 = es[j + 2], s3 = es[j + 3];
        f16x2 v0 = y2[(size_t)s0 * 64 + lane];
        f16x2 v1 = y2[(size_t)s1 * 64 + lane];
        f16x2 v2 = y2[(size_t)s2 * 64 + lane];
        f16x2 v3 = y2[(size_t)s3 * 64 + lane];
        ax += (float)v0[0] + (float)v1[0] + (float)v2[0] + (float)v3[0];
        ay += (float)v0[1] + (float)v1[1] + (float)v2[1] + (float)v3[1];
    }
    for (; j < end; j++) {
        f16x2 v0 = y2[(size_t)es[j] * 64 + lane];
        ax += (float)v0[0];
        ay += (float)v0[1];
    }
    float ndv = nd[node];
    float2 b = ((const float2*)bias)[lane];
    float ox = fmaf(ax, ndv, b.x);
    float oy = fmaf(ay, ndv, b.y);
    if (relu) { ox = ox > 0.f ? ox : 0.f; oy = oy > 0.f ? oy : 0.f; }
    ((float2*)Out)[(size_t)node * 64 + lane] = make_float2(ox, oy);
}

// ---------------- host ----------------

static inline int ceil_div(int a, int b) { return (a + b - 1) / b; }

struct TypeBufs {
    int *rowptr, *esrc, *ch, *bb;
    u32 *binned, *part;
    float *norm_s, *norm_d, *h;
    f16* y;
    bf16 *wth0, *wtl0, *wth1, *wtl1;
};

extern "C" void kernel_launch(void* const* d_in, const int* in_sizes, int n_in,
                              void* d_out, int out_size, void* d_ws, size_t ws_size,
                              hipStream_t stream) {
    (void)n_in; (void)out_size; (void)ws_size;
    const float* feat_a = (const float*)d_in[0];
    const float* feat_b = (const float*)d_in[1];
    const int* src_a = (const int*)d_in[2];
    const int* dst_a = (const int*)d_in[3];
    const int* src_b = (const int*)d_in[4];
    const int* dst_b = (const int*)d_in[5];
    const float* Wa0 = (const float*)d_in[6];
    const float* ba0 = (const float*)d_in[7];
    const float* Wa1 = (const float*)d_in[8];
    const float* ba1 = (const float*)d_in[9];
    const float* Wb0 = (const float*)d_in[10];
    const float* bb0 = (const float*)d_in[11];
    const float* Wb1 = (const float*)d_in[12];
    const float* bb1 = (const float*)d_in[13];

    const int DA = in_sizes[6] / H;   // 256
    const int DB = in_sizes[10] / H;  // 128
    const int NA = in_sizes[0] / DA;  // 50000
    const int NB = in_sizes[1] / DB;  // 30000
    const int EA = in_sizes[2];       // 600000
    const int EB = in_sizes[4];       // 300000

    const int nblkA = ceil_div(EA, EPB), nblkB = ceil_div(EB, EPB);
    const int nbinsA = ceil_div(NA, BUCK), nbinsB = ceil_div(NB, BUCK);
    const int LA = nbinsA * nblkA, LB = nbinsB * nblkB;
    const int nchA = ceil_div(NA, CHN), nchB = ceil_div(NB, CHN);

    char* w = (char*)d_ws;
    auto carve = [&](size_t bytes) {
        void* p = (void*)w;
        w += (bytes + 255) & ~(size_t)255;
        return p;
    };
    auto carve_type = [&](int N, int E, int D, int L, int nbins, int nch, int sl) {
        TypeBufs tb;
        tb.rowptr = (int*)carve(((size_t)N + 1) * 4);
        tb.esrc   = (int*)carve((size_t)E * 4);
        tb.ch     = (int*)carve((size_t)L * 4);
        tb.bb     = (int*)carve(((size_t)nbins + 1) * 4);
        tb.binned = (u32*)carve((size_t)E * 4);
        tb.part   = (u32*)carve((size_t)nch * sl * SLOTS * 4);
        tb.norm_s = (float*)carve((size_t)N * 4);
        tb.norm_d = (float*)carve((size_t)N * 4);
        tb.h      = (float*)carve((size_t)N * H * 4);
        tb.y      = (f16*)carve((size_t)N * H * 2);
        tb.wth0   = (bf16*)carve((size_t)D * H * 2);
        tb.wtl0   = (bf16*)carve((size_t)D * H * 2);
        tb.wth1   = (bf16*)carve((size_t)H * H * 2);
        tb.wtl1   = (bf16*)carve((size_t)H * H * 2);
        return tb;
    };
    TypeBufs A = carve_type(NA, EA, DA, LA, nbinsA, nchA, SLA);
    TypeBufs B = carve_type(NB, EB, DB, LB, nbinsB, nchB, SLB);

    float* out_a = (float*)d_out;
    float* out_b = out_a + (size_t)NA * H;

    const int gblkA = ceil_div(NA, 64), gblkB = ceil_div(NB, 64);
    const int nA4 = ceil_div(NA, 4), nB4 = ceil_div(NB, 4);

    // ---- graph prep (no device-scope atomics anywhere) ----
    p1K<<<nblkA + nblkB, 256, 0, stream>>>(dst_a, A.ch, EA, nblkA, nbinsA,
                                           dst_b, B.ch, EB, nblkB, nbinsB);
    doHistK<<<nchA * SLA + nchB * SLB, 256, 0, stream>>>(src_a, EA, A.part, NA,
                                                         src_b, EB, B.part, NB);
    p2K<<<2, 256, 0, stream>>>(A.ch, LA, A.bb, nbinsA, nblkA, EA, A.rowptr, NA,
                               B.ch, LB, B.bb, nbinsB, nblkB, EB, B.rowptr, NB);
    doRedK<<<ceil_div(NA + NB, 256), 256, 0, stream>>>(A.part, A.norm_s, NA,
                                                       B.part, B.norm_s, NB);
    p3K<<<nblkA + nblkB, 256, 0, stream>>>(src_a, dst_a, A.ch, A.binned, EA, nblkA, nbinsA,
                                           src_b, dst_b, B.ch, B.binned, EB, nblkB, nbinsB);
    p4K<<<nbinsA + nbinsB, 256, 0, stream>>>(A.binned, A.bb, nbinsA, A.rowptr, A.norm_d, A.esrc, NA,
                                             B.binned, B.bb, nbinsB, B.rowptr, B.norm_d, B.esrc, NB);
    wconvAB<<<DA + 3 * H, H, 0, stream>>>(Wa0, A.wth0, A.wtl0, Wa1, A.wth1, A.wtl1,
                                          Wb0, B.wth0, B.wtl0, Wb1, B.wth1, B.wtl1, DA);
    // ---- layer 0 ----
    gemmAB<<<gblkA + gblkB, 256, 0, stream>>>(
        feat_a, A.wth0, A.wtl0, A.norm_s, A.y, NA, DA, gblkA,
        feat_b, B.wth0, B.wtl0, B.norm_s, B.y, NB, DB);
    aggAB<<<nA4 + nB4, 256, 0, stream>>>(
        A.y, A.rowptr, A.esrc, A.norm_d, ba0, A.h, nA4, NA,
        B.y, B.rowptr, B.esrc, B.norm_d, bb0, B.h, NB, 1);
    // ---- layer 1 ----
    gemmAB<<<gblkA + gblkB, 256, 0, stream>>>(
        A.h, A.wth1, A.wtl1, A.norm_s, A.y, NA, H, gblkA,
        B.h, B.wth1, B.wtl1, B.norm_s, B.y, NB, H);
    aggAB<<<nA4 + nB4, 256, 0, stream>>>(
        A.y, A.rowptr, A.esrc, A.norm_d, ba1, out_a, nA4, NA,
        B.y, B.rowptr, B.esrc, B.norm_d, bb1, out_b, NB, 0);
}